// Round 2
// baseline (588.998 us; speedup 1.0000x reference)
//
#include <hip/hip_runtime.h>

// BlockEnd: out[b,a,f] = (a < M[b]) ? relu( sum_r resid[b,a,r]*w[r,f] + node[b,a,f] ) : 0
// B=4096, A=RF=F=128. fp32 in/out; bf16 MFMA compute (tolerance allows, R0 absmax 0.031).
//
// R1 changes vs R0 (which hit 175us at 2.4 TB/s, latency-bound):
//  - wT staged ONCE per block into LDS in *fragment order*: slot (ft*4+kk)*64+lane,
//    so the K-loop reads are ds_read_b128 at base+lane*16 (conflict-free, aligned),
//    and the vmcnt queue carries only resid/node/out traffic.
//  - 2 molecules per block (grid 2048) to amortize staging + give a pipelineable loop.
//  - ft split into two halves: acc = 32 VGPRs (not 64) -> __launch_bounds__(256,4).
//  - resid row loads predicated on row < M (rows >= M contribute only to discarded cols).
//  - nontemporal output stores (out is never re-read; keep L2/L3 for inputs).

typedef __bf16 bf16x8 __attribute__((ext_vector_type(8)));
typedef float f32x4 __attribute__((ext_vector_type(4)));

static_assert(sizeof(bf16x8) == 16, "bf16x8 must be 16B");
static_assert(sizeof(f32x4) == 16, "f32x4 must be 16B");

#define PB 2  // molecules per block

// wT[f*128 + r] = (bf16) w[r*128 + f]
__global__ __launch_bounds__(256) void wT_kernel(const float* __restrict__ w,
                                                 __bf16* __restrict__ wT) {
    int i = blockIdx.x * 256 + threadIdx.x;   // 0..16383
    int f = i >> 7;
    int r = i & 127;
    wT[i] = (__bf16)w[r * 128 + f];
}

__global__ __launch_bounds__(256, 4) void blockend_kernel(
    const float* __restrict__ node,    // [B,128,128]
    const float* __restrict__ resid,   // [B,128,128]
    const __bf16* __restrict__ wTg,    // [128(f),128(r)] bf16 (global, from wT_kernel)
    const int*   __restrict__ mol,     // [B,2] int32, M = mol[2b]
    float*       __restrict__ out)     // [B,128,128]
{
    // Fragment-ordered wT: slot s = ft*256 + kk*64 + quad*16 + m16 holds
    // wT[row f = ft*16+m16][k = kk*32+quad*8 .. +8)  (one 16B bf16x8 chunk).
    __shared__ bf16x8 wlds[2048];      // 32 KB

    const int t    = threadIdx.x;
    const int wave = t >> 6;
    const int lane = t & 63;
    const int quad = lane >> 4;
    const int m16  = lane & 15;

    // Stage wT -> LDS (coalesced global reads; scattered-but-cheap LDS writes, once/block).
#pragma unroll
    for (int i = 0; i < 8; ++i) {
        int c   = t + i * 256;         // source 16B chunk: row f = c>>4, pos = c&15
        int f   = c >> 4;
        int pos = c & 15;              // = kk*4 + quad
        bf16x8 v = *(const bf16x8*)(wTg + c * 8);
        int s = (f >> 4) * 256 + (pos >> 2) * 64 + (pos & 3) * 16 + (f & 15);
        wlds[s] = v;
    }
    __syncthreads();

    const int a_base = wave * 32;

    for (int mi = 0; mi < PB; ++mi) {
        const int b = blockIdx.x * PB + mi;
        const int M = mol[2 * b];
        const size_t base = (size_t)b * (128 * 128);
        float* outW = out + base + (size_t)a_base * 128;

        if (M <= a_base) {
            // whole wave masked: 32 rows of zeros, coalesced float4 nt-stores
            f32x4 z = {0.f, 0.f, 0.f, 0.f};
            f32x4* p = (f32x4*)outW;
#pragma unroll
            for (int it = 0; it < 16; ++it)
                __builtin_nontemporal_store(z, p + it * 64 + lane);
            continue;
        }

        // B-operand fragments: resid rows, predicated per row (row >= M -> zeros).
        bf16x8 rfrag[2][4];
#pragma unroll
        for (int nt = 0; nt < 2; ++nt) {
            const int row  = a_base + nt * 16 + m16;
            const bool act = row < M;
            const float* rp = resid + base + (size_t)row * 128 + quad * 8;
#pragma unroll
            for (int kk = 0; kk < 4; ++kk) {
                f32x4 lo = {0.f, 0.f, 0.f, 0.f};
                f32x4 hi = {0.f, 0.f, 0.f, 0.f};
                if (act) {
                    lo = *(const f32x4*)(rp + kk * 32);
                    hi = *(const f32x4*)(rp + kk * 32 + 4);
                }
                bf16x8 v;
                v[0] = (__bf16)lo[0]; v[1] = (__bf16)lo[1];
                v[2] = (__bf16)lo[2]; v[3] = (__bf16)lo[3];
                v[4] = (__bf16)hi[0]; v[5] = (__bf16)hi[1];
                v[6] = (__bf16)hi[2]; v[7] = (__bf16)hi[3];
                rfrag[nt][kk] = v;
            }
        }

        const float* nodeW = node + base + (size_t)a_base * 128;

        // Two ft-halves: acc pressure 32 VGPRs instead of 64.
#pragma unroll
        for (int h = 0; h < 2; ++h) {
            f32x4 acc[2][4];
#pragma unroll
            for (int nt = 0; nt < 2; ++nt)
#pragma unroll
                for (int fl = 0; fl < 4; ++fl)
                    acc[nt][fl] = (f32x4){0.f, 0.f, 0.f, 0.f};

#pragma unroll
            for (int kk = 0; kk < 4; ++kk)
#pragma unroll
                for (int fl = 0; fl < 4; ++fl) {
                    bf16x8 wf = wlds[((h * 4 + fl) * 4 + kk) * 64 + lane];
                    acc[0][fl] = __builtin_amdgcn_mfma_f32_16x16x32_bf16(
                        wf, rfrag[0][kk], acc[0][fl], 0, 0, 0);
                    acc[1][fl] = __builtin_amdgcn_mfma_f32_16x16x32_bf16(
                        wf, rfrag[1][kk], acc[1][fl], 0, 0, 0);
                }

            // Epilogue for this half. D[m=f][n=a]: f = ft*16 + quad*4 + reg, a = nt*16+m16.
#pragma unroll
            for (int nt = 0; nt < 2; ++nt) {
                const int a_local = nt * 16 + m16;
                const bool active = (a_base + a_local) < M;
#pragma unroll
                for (int fl = 0; fl < 4; ++fl) {
                    const int off = a_local * 128 + (h * 4 + fl) * 16 + quad * 4;
                    f32x4 v = {0.f, 0.f, 0.f, 0.f};
                    if (active) {
                        f32x4 nd = *(const f32x4*)(nodeW + off);
#pragma unroll
                        for (int i = 0; i < 4; ++i) {
                            float x = acc[nt][fl][i] + nd[i];
                            v[i] = x > 0.f ? x : 0.f;
                        }
                    }
                    __builtin_nontemporal_store(v, (f32x4*)(outW + off));
                }
            }
        }
    }
}

extern "C" void kernel_launch(void* const* d_in, const int* in_sizes, int n_in,
                              void* d_out, int out_size, void* d_ws, size_t ws_size,
                              hipStream_t stream) {
    const float* node  = (const float*)d_in[0];   // node_features    [4096,128,128]
    const float* resid = (const float*)d_in[1];   // residual_features[4096,128,128]
    const float* w     = (const float*)d_in[2];   // w [128,128]
    const int*   mol   = (const int*)d_in[3];     // mol_slice [4096,2] int32
    float*       out   = (float*)d_out;
    __bf16*      wT    = (__bf16*)d_ws;           // 32 KB scratch

    wT_kernel<<<64, 256, 0, stream>>>(w, wT);
    blockend_kernel<<<4096 / PB, 256, 0, stream>>>(node, resid, wT, mol, out);
}